// Round 1
// baseline (284.097 us; speedup 1.0000x reference)
//
#include <hip/hip_runtime.h>

typedef __attribute__((ext_vector_type(8))) __bf16 bf16x8;
typedef __attribute__((ext_vector_type(4))) float floatx4;
typedef unsigned short u16;

__device__ __forceinline__ u16 f2bf(float f) {
    union { float f; unsigned int u; } v; v.f = f;
    unsigned int r = v.u + 0x7fffu + ((v.u >> 16) & 1u);
    return (u16)(r >> 16);
}

// ---------------- transpose fp32 -> bf16, out[c][r] = bf16(in[r][c]) ----------------
__global__ __launch_bounds__(256) void transpose_bf16(const float* __restrict__ in, u16* __restrict__ out,
                                                      int rows, int cols) {
    __shared__ float tile[64][68];
    const int t = threadIdx.x;
    const int tr = blockIdx.y * 64, tc = blockIdx.x * 64;
    for (int p = 0; p < 4; p++) {
        int ri = (t >> 4) + p * 16;
        int ci = (t & 15) * 4;
        float4 v = *(const float4*)&in[(size_t)(tr + ri) * cols + tc + ci];
        tile[ri][ci + 0] = v.x; tile[ri][ci + 1] = v.y;
        tile[ri][ci + 2] = v.z; tile[ri][ci + 3] = v.w;
    }
    __syncthreads();
    for (int p = 0; p < 4; p++) {
        int oc = (t >> 4) + p * 16;
        int ir = (t & 15) * 4;
        ushort4 o;
        o.x = f2bf(tile[ir + 0][oc]);
        o.y = f2bf(tile[ir + 1][oc]);
        o.z = f2bf(tile[ir + 2][oc]);
        o.w = f2bf(tile[ir + 3][oc]);
        *(ushort4*)&out[(size_t)(tc + oc) * rows + tr + ir] = o;
    }
}

// ---------------- LayerNorm -> bf16 ----------------
__global__ __launch_bounds__(256) void ln_kernel(const float* __restrict__ x, const float* __restrict__ gamma,
                                                 const float* __restrict__ beta, u16* __restrict__ xn) {
    const int row = blockIdx.x, t = threadIdx.x;
    const float* xr = x + (size_t)row * 1024;
    float4 v = *(const float4*)&xr[t * 4];
    float s = v.x + v.y + v.z + v.w;
    float s2 = v.x * v.x + v.y * v.y + v.z * v.z + v.w * v.w;
    for (int off = 1; off < 64; off <<= 1) {
        s += __shfl_xor(s, off, 64);
        s2 += __shfl_xor(s2, off, 64);
    }
    __shared__ float ps[4], ps2[4];
    int w = t >> 6, lane = t & 63;
    if (lane == 0) { ps[w] = s; ps2[w] = s2; }
    __syncthreads();
    float S = ps[0] + ps[1] + ps[2] + ps[3];
    float S2 = ps2[0] + ps2[1] + ps2[2] + ps2[3];
    float mu = S * (1.0f / 1024.0f);
    float var = S2 * (1.0f / 1024.0f) - mu * mu;
    float rstd = rsqrtf(var + 1e-5f);
    ushort4 o;
    o.x = f2bf((v.x - mu) * rstd * gamma[t * 4 + 0] + beta[t * 4 + 0]);
    o.y = f2bf((v.y - mu) * rstd * gamma[t * 4 + 1] + beta[t * 4 + 1]);
    o.z = f2bf((v.z - mu) * rstd * gamma[t * 4 + 2] + beta[t * 4 + 2]);
    o.w = f2bf((v.w - mu) * rstd * gamma[t * 4 + 3] + beta[t * 4 + 3]);
    *(ushort4*)&xn[(size_t)row * 1024 + t * 4] = o;
}

// ---------------- C = A(MxK) @ BT(NxK)^T, bf16 in, 128x128x32 tiles ----------------
template <bool FINAL>
__global__ __launch_bounds__(256) void gemm_bt(const u16* __restrict__ A, const u16* __restrict__ BT,
                                               u16* __restrict__ Cb, float* __restrict__ Cf,
                                               const float* __restrict__ bias, const float* __restrict__ resid,
                                               int M, int N, int K) {
    __shared__ u16 as_[128 * 40];  // stride 40 (80B rows, 16B aligned, 2-way bank alias max)
    __shared__ u16 bs_[128 * 40];
    const int t = threadIdx.x;
    const int w = t >> 6, lane = t & 63, q = lane >> 4, c = lane & 15;
    const int tm = blockIdx.y * 128, tn = blockIdx.x * 128;
    const int wm = (w & 1) * 64, wn = (w >> 1) * 64;
    floatx4 acc[4][4];
    for (int i = 0; i < 4; i++)
        for (int j = 0; j < 4; j++) acc[i][j] = (floatx4){0.f, 0.f, 0.f, 0.f};
    for (int k0 = 0; k0 < K; k0 += 32) {
        __syncthreads();
        for (int i = 0; i < 2; i++) {
            int ch = t + i * 256;
            int row = ch >> 2, off = (ch & 3) * 8;
            *(uint4*)&as_[row * 40 + off] = *(const uint4*)&A[(size_t)(tm + row) * K + k0 + off];
            *(uint4*)&bs_[row * 40 + off] = *(const uint4*)&BT[(size_t)(tn + row) * K + k0 + off];
        }
        __syncthreads();
        bf16x8 af[4], bf[4];
        for (int i = 0; i < 4; i++) af[i] = *(const bf16x8*)&as_[(wm + i * 16 + c) * 40 + q * 8];
        for (int j = 0; j < 4; j++) bf[j] = *(const bf16x8*)&bs_[(wn + j * 16 + c) * 40 + q * 8];
        for (int i = 0; i < 4; i++)
            for (int j = 0; j < 4; j++)
                acc[i][j] = __builtin_amdgcn_mfma_f32_16x16x32_bf16(af[i], bf[j], acc[i][j], 0, 0, 0);
    }
    for (int i = 0; i < 4; i++)
        for (int j = 0; j < 4; j++)
            for (int r = 0; r < 4; r++) {
                int row = tm + wm + i * 16 + q * 4 + r;
                int col = tn + wn + j * 16 + c;
                if (FINAL)
                    Cf[(size_t)row * N + col] = acc[i][j][r] + bias[col] + resid[(size_t)row * N + col];
                else
                    Cb[(size_t)row * N + col] = f2bf(acc[i][j][r]);
            }
}

// ---------------- flash attention, MQA: qkv row = [q(1024) | k(64) | v(64)] ----------------
__global__ __launch_bounds__(256) void attn_kernel(const u16* __restrict__ qkv, u16* __restrict__ out) {
    __shared__ u16 ksm[64 * 72];      // [s][d], pad to 72
    __shared__ u16 vsm[64 * 72];      // [d][s] transposed
    __shared__ u16 psm[4][32 * 72];   // per-wave P round-trip buffer
    const int t = threadIdx.x;
    const int w = t >> 6, lane = t & 63, q = lane >> 4, c = lane & 15;
    const int qt = blockIdx.x, h = blockIdx.y, b = blockIdx.z;
    u16* pw = psm[w];
    const size_t rowbase = (size_t)(b * 2048 + qt * 128 + w * 32);

    bf16x8 qf[2][2];
    for (int mi = 0; mi < 2; mi++)
        for (int kk = 0; kk < 2; kk++)
            qf[mi][kk] = *(const bf16x8*)&qkv[(rowbase + mi * 16 + c) * 1152 + h * 64 + kk * 32 + q * 8];

    float M_[2][4], L_[2][4];
    floatx4 O_[2][4];
    for (int mi = 0; mi < 2; mi++)
        for (int r = 0; r < 4; r++) { M_[mi][r] = -1e30f; L_[mi][r] = 0.f; }
    for (int mi = 0; mi < 2; mi++)
        for (int di = 0; di < 4; di++) O_[mi][di] = (floatx4){0.f, 0.f, 0.f, 0.f};

    for (int s0 = 0; s0 < 2048; s0 += 64) {
        __syncthreads();
        for (int i = 0; i < 2; i++) {
            int ch = t + i * 256;
            int row = ch >> 3, off = (ch & 7) * 8;
            size_t gbase = (size_t)(b * 2048 + s0 + row) * 1152;
            *(uint4*)&ksm[row * 72 + off] = *(const uint4*)&qkv[gbase + 1024 + off];
            uint4 vv4 = *(const uint4*)&qkv[gbase + 1088 + off];
            const u16* vv = (const u16*)&vv4;
            for (int j = 0; j < 8; j++) vsm[(off + j) * 72 + row] = vv[j];
        }
        __syncthreads();

        bf16x8 kf[4][2];
        for (int ni = 0; ni < 4; ni++)
            for (int kk = 0; kk < 2; kk++)
                kf[ni][kk] = *(const bf16x8*)&ksm[(ni * 16 + c) * 72 + kk * 32 + q * 8];

        floatx4 sacc[2][4];
        for (int mi = 0; mi < 2; mi++)
            for (int ni = 0; ni < 4; ni++) {
                floatx4 z = (floatx4){0.f, 0.f, 0.f, 0.f};
                z = __builtin_amdgcn_mfma_f32_16x16x32_bf16(qf[mi][0], kf[ni][0], z, 0, 0, 0);
                z = __builtin_amdgcn_mfma_f32_16x16x32_bf16(qf[mi][1], kf[ni][1], z, 0, 0, 0);
                sacc[mi][ni] = z;
            }
        for (int mi = 0; mi < 2; mi++)
            for (int ni = 0; ni < 4; ni++)
                for (int r = 0; r < 4; r++) sacc[mi][ni][r] *= 0.125f;

        for (int mi = 0; mi < 2; mi++) {
            float rmax[4];
            for (int r = 0; r < 4; r++) {
                float m = -1e30f;
                for (int ni = 0; ni < 4; ni++) m = fmaxf(m, sacc[mi][ni][r]);
                rmax[r] = m;
            }
            for (int off = 1; off < 16; off <<= 1)
                for (int r = 0; r < 4; r++) rmax[r] = fmaxf(rmax[r], __shfl_xor(rmax[r], off, 64));
            for (int r = 0; r < 4; r++) {
                float Mnew = fmaxf(M_[mi][r], rmax[r]);
                float alpha = __expf(M_[mi][r] - Mnew);
                M_[mi][r] = Mnew;
                float ls = 0.f;
                for (int ni = 0; ni < 4; ni++) {
                    float p = __expf(sacc[mi][ni][r] - Mnew);
                    ls += p;
                    pw[(mi * 16 + q * 4 + r) * 72 + ni * 16 + c] = f2bf(p);
                }
                for (int off = 1; off < 16; off <<= 1) ls += __shfl_xor(ls, off, 64);
                L_[mi][r] = L_[mi][r] * alpha + ls;
                for (int di = 0; di < 4; di++) O_[mi][di][r] *= alpha;
            }
        }

        bf16x8 pf[2][2], vf[4][2];
        for (int mi = 0; mi < 2; mi++)
            for (int kk = 0; kk < 2; kk++)
                pf[mi][kk] = *(const bf16x8*)&pw[(mi * 16 + c) * 72 + kk * 32 + q * 8];
        for (int di = 0; di < 4; di++)
            for (int kk = 0; kk < 2; kk++)
                vf[di][kk] = *(const bf16x8*)&vsm[(di * 16 + c) * 72 + kk * 32 + q * 8];
        for (int mi = 0; mi < 2; mi++)
            for (int di = 0; di < 4; di++) {
                O_[mi][di] = __builtin_amdgcn_mfma_f32_16x16x32_bf16(pf[mi][0], vf[di][0], O_[mi][di], 0, 0, 0);
                O_[mi][di] = __builtin_amdgcn_mfma_f32_16x16x32_bf16(pf[mi][1], vf[di][1], O_[mi][di], 0, 0, 0);
            }
    }

    for (int mi = 0; mi < 2; mi++)
        for (int di = 0; di < 4; di++)
            for (int r = 0; r < 4; r++) {
                float o = O_[mi][di][r] / L_[mi][r];
                size_t row = rowbase + mi * 16 + q * 4 + r;
                out[row * 1024 + h * 64 + di * 16 + c] = f2bf(o);
            }
}

extern "C" void kernel_launch(void* const* d_in, const int* in_sizes, int n_in,
                              void* d_out, int out_size, void* d_ws, size_t ws_size,
                              hipStream_t stream) {
    const float* x = (const float*)d_in[0];
    const float* gamma = (const float*)d_in[1];
    const float* beta = (const float*)d_in[2];
    const float* Wq = (const float*)d_in[3];
    const float* Wkv = (const float*)d_in[4];
    const float* Wo = (const float*)d_in[5];
    const float* bo = (const float*)d_in[6];
    float* out = (float*)d_out;

    u16* WqkvT = (u16*)d_ws;                         // 1152*1024
    u16* WoT = WqkvT + (size_t)1152 * 1024;          // 1024*1024
    u16* xn = WoT + (size_t)1024 * 1024;             // 4096*1024
    u16* qkv = xn + (size_t)4096 * 1024;             // 4096*1152
    u16* attnO = xn;                                 // alias: xn dead after QKV GEMM

    transpose_bf16<<<dim3(16, 16), 256, 0, stream>>>(Wq, WqkvT, 1024, 1024);
    transpose_bf16<<<dim3(2, 16), 256, 0, stream>>>(Wkv, WqkvT + (size_t)1024 * 1024, 1024, 128);
    transpose_bf16<<<dim3(16, 16), 256, 0, stream>>>(Wo, WoT, 1024, 1024);
    ln_kernel<<<4096, 256, 0, stream>>>(x, gamma, beta, xn);
    gemm_bt<false><<<dim3(9, 32), 256, 0, stream>>>(xn, WqkvT, qkv, nullptr, nullptr, nullptr, 4096, 1152, 1024);
    attn_kernel<<<dim3(16, 16, 2), 256, 0, stream>>>(qkv, attnO);
    gemm_bt<true><<<dim3(8, 32), 256, 0, stream>>>(attnO, WoT, nullptr, out, bo, x, 4096, 1024, 1024);
}